// Round 4
// baseline (382.754 us; speedup 1.0000x reference)
//
#include <hip/hip_runtime.h>

// Aggregate = column segment-sum: out[b][g] = sum_{c: sid[c]==g} x[b][c]
// x: [8192, 8192] f32, sid: [8192] i32 in [0,512), out: [8192, 512] f32.
//
// R1: LDS atomic scatter = lane-serial atomic unit, 341us, all pipes idle.
// R2: CSR gather, 167us: 2 barriers/row @ 2 blocks/CU serialize phases.
// R3: row pairs + nontemporal + 1 barrier/row: ~90us (bench 362 total; k_main
//     hidden below harness 1GB poison fills which run at 6.6 TB/s = BW proof).
// R4: occupancy. 80KB LDS allowed only 2 blocks/CU -> barrier+vmcnt drains
//     exposed. Single-row staging: rowb 32KB + col16 16KB = 48KB -> 3
//     blocks/CU; 3 blocks rotate through drains, keeping HBM issue busy.
//     LDS gather pipe (~8.3k cyc/row-phase/CU) stays under HBM (~9.8k).

#define NCLS 8192
#define NGRP 512
#define ROWS 8
#define TPB  256

typedef float vf4 __attribute__((ext_vector_type(4)));
typedef float vf2 __attribute__((ext_vector_type(2)));

// d_ws layout (ints): hist[512] @0, offs[513] @512, curs[512] @1088, cols[8192] @1600

__global__ __launch_bounds__(512) void k_hist(const int* __restrict__ sid,
                                              int* __restrict__ hist) {
    int i = blockIdx.x * 512 + threadIdx.x;
    atomicAdd(&hist[sid[i]], 1);
}

__global__ __launch_bounds__(512) void k_scan(const int* __restrict__ hist,
                                              int* __restrict__ offs,
                                              int* __restrict__ curs) {
    __shared__ int tmp[NGRP];
    const int t = threadIdx.x;
    const int h = hist[t];
    tmp[t] = h;
    __syncthreads();
    for (int off = 1; off < NGRP; off <<= 1) {
        int v = tmp[t];
        int u = (t >= off) ? tmp[t - off] : 0;
        __syncthreads();
        tmp[t] = v + u;
        __syncthreads();
    }
    int excl = tmp[t] - h;   // exclusive prefix sum
    offs[t] = excl;
    curs[t] = excl;
    if (t == NGRP - 1) offs[NGRP] = NCLS;
}

__global__ __launch_bounds__(512) void k_scatter(const int* __restrict__ sid,
                                                 int* __restrict__ curs,
                                                 int* __restrict__ cols) {
    int c = blockIdx.x * 512 + threadIdx.x;
    int g = sid[c];
    int pos = atomicAdd(&curs[g], 1);  // order within group irrelevant (sum)
    cols[pos] = c;
}

__global__ __launch_bounds__(TPB) void k_main(const float* __restrict__ x,
                                              const int* __restrict__ cols,
                                              const int* __restrict__ offs,
                                              float* __restrict__ out) {
    __shared__ float rowb[NCLS];             // 32 KB: one row
    __shared__ unsigned short col16[NCLS];   // 16 KB: CSR column ids (u16)
    const int tid  = threadIdx.x;
    const int row0 = blockIdx.x * ROWS;

    // Cache CSR column list in LDS (u16), vectorized.
    for (int i = tid; i < NCLS / 4; i += TPB) {
        int4 c = reinterpret_cast<const int4*>(cols)[i];
        ushort4 u;
        u.x = (unsigned short)c.x; u.y = (unsigned short)c.y;
        u.z = (unsigned short)c.z; u.w = (unsigned short)c.w;
        *reinterpret_cast<ushort4*>(&col16[4 * i]) = u;
    }

    // Thread owns groups 2*tid and 2*tid+1.
    const int s0 = offs[2 * tid];
    const int e0 = offs[2 * tid + 1];
    const int e1 = offs[2 * tid + 2];

    // Preload row 0 into registers (nontemporal: x has zero reuse).
    vf4 v[8];
    {
        const float* xr = x + (size_t)row0 * NCLS;
#pragma unroll
        for (int k = 0; k < 8; ++k)
            v[k] = __builtin_nontemporal_load(
                reinterpret_cast<const vf4*>(xr + k * 1024 + tid * 4));
    }
    __syncthreads();  // col16 ready
#pragma unroll
    for (int k = 0; k < 8; ++k)
        *reinterpret_cast<vf4*>(&rowb[k * 1024 + tid * 4]) = v[k];

    for (int r = 0; r < ROWS; ++r) {
        __syncthreads();  // rowb for row r visible to all

        // Issue prefetch of row r+1 (non-blocking) before gathering row r.
        if (r + 1 < ROWS) {
            const float* xr = x + (size_t)(row0 + r + 1) * NCLS;
#pragma unroll
            for (int k = 0; k < 8; ++k)
                v[k] = __builtin_nontemporal_load(
                    reinterpret_cast<const vf4*>(xr + k * 1024 + tid * 4));
        }

        // Gather this row's two group-sums from LDS.
        float sum0 = 0.f, sum1 = 0.f;
        for (int p = s0; p < e0; ++p) sum0 += rowb[col16[p]];
        for (int p = e0; p < e1; ++p) sum1 += rowb[col16[p]];

        {
            vf2 o; o.x = sum0; o.y = sum1;
            __builtin_nontemporal_store(
                o, reinterpret_cast<vf2*>(out + (size_t)(row0 + r) * NGRP + 2 * tid));
        }

        __syncthreads();  // all reads of rowb done before overwrite
        if (r + 1 < ROWS) {
#pragma unroll
            for (int k = 0; k < 8; ++k)
                *reinterpret_cast<vf4*>(&rowb[k * 1024 + tid * 4]) = v[k];
        }
    }
}

extern "C" void kernel_launch(void* const* d_in, const int* in_sizes, int n_in,
                              void* d_out, int out_size, void* d_ws, size_t ws_size,
                              hipStream_t stream) {
    const float* x   = (const float*)d_in[0];
    const int*   sid = (const int*)d_in[1];
    float*       out = (float*)d_out;

    int* ws   = (int*)d_ws;
    int* hist = ws;
    int* offs = ws + 512;
    int* curs = ws + 1088;
    int* cols = ws + 1600;

    const int batch  = in_sizes[0] / NCLS;   // 8192
    const int blocks = batch / ROWS;         // 1024

    hipMemsetAsync(hist, 0, NGRP * sizeof(int), stream);
    k_hist<<<NCLS / 512, 512, 0, stream>>>(sid, hist);
    k_scan<<<1, NGRP, 0, stream>>>(hist, offs, curs);
    k_scatter<<<NCLS / 512, 512, 0, stream>>>(sid, curs, cols);
    k_main<<<blocks, TPB, 0, stream>>>(x, cols, offs, out);
}